// Round 1
// 686.106 us; speedup vs baseline: 1.0280x; 1.0280x over previous
//
#include <hip/hip_runtime.h>
#include <math.h>

constexpr int N = 10000;   // nodes
constexpr int E = 50000;   // edges
constexpr int D = 32;      // dim
constexpr int H = 4;       // heads

typedef float v4f __attribute__((ext_vector_type(4)));

// ---------------------------------------------------------------------------
// Edge kernel: per-edge hypernetwork matvecs + logit + exp, then ATOMIC
// accumulation of exp (denominator) and exp*V (unnormalized aggregate)
// directly into per-node buffers. Softmax normalization commutes with the
// weighted sum, so no CSR / edge-list pass is needed at all.
//
// One block (256 threads) per edge; thread t: hd = t>>3, seg = t&7; each
// thread does ONE nontemporal float4 load per weight tensor (coalesced,
// read-once streams). Wave w == head w.
// ---------------------------------------------------------------------------
__global__ __launch_bounds__(256) void edge_kernel(
    const float* __restrict__ in_feat,
    const int*   __restrict__ src, const int* __restrict__ dst,
    const float* __restrict__ skw, const float* __restrict__ dkw,
    const float* __restrict__ skb, const float* __restrict__ dkb,
    const float* __restrict__ svw, const float* __restrict__ dvw,
    const float* __restrict__ svb, const float* __restrict__ dvb,
    const float* __restrict__ query,
    float* __restrict__ key_feat, float* __restrict__ value_feat,
    float* __restrict__ ex_out,   // attn slot of d_out; holds exp(logit)
    float* __restrict__ aggU,     // (N, D) unnormalized aggregate (= out slot)
    float* __restrict__ denom)    // (N, H) softmax denominator (workspace)
{
    const int e   = blockIdx.x;
    const int tid = threadIdx.x;
    const int hd  = tid >> 3;   // 0..31  (= h*8 + d_local)
    const int seg = tid & 7;    // 0..7
    const int s = src[e];
    const int d = dst[e];

    const float4 u4 = *reinterpret_cast<const float4*>(in_feat + s * D + seg * 4);
    const float4 v4 = *reinterpret_cast<const float4*>(in_feat + d * D + seg * 4);

    const size_t woff = (size_t)e * 1024 + (size_t)tid * 4;
    const v4f wa = __builtin_nontemporal_load(reinterpret_cast<const v4f*>(skw + woff));
    const v4f wb = __builtin_nontemporal_load(reinterpret_cast<const v4f*>(dkw + woff));
    const v4f wc = __builtin_nontemporal_load(reinterpret_cast<const v4f*>(svw + woff));
    const v4f wd = __builtin_nontemporal_load(reinterpret_cast<const v4f*>(dvw + woff));

    float pk = wa.x * u4.x + wa.y * u4.y + wa.z * u4.z + wa.w * u4.w
             + wb.x * v4.x + wb.y * v4.y + wb.z * v4.z + wb.w * v4.w;
    float pv = wc.x * u4.x + wc.y * u4.y + wc.z * u4.z + wc.w * u4.w
             + wd.x * v4.x + wd.y * v4.y + wd.z * v4.z + wd.w * v4.w;

    #pragma unroll
    for (int off = 1; off < 8; off <<= 1) {
        pk += __shfl_xor(pk, off);
        pv += __shfl_xor(pv, off);
    }

    // only seg==0 lanes need biases / K / V / query
    const int bi = e * D + hd;
    float c  = 0.0f;
    float Vv = 0.0f;
    if (seg == 0) {
        const float Kv = pk + skb[bi] + dkb[bi];
        Vv = pv + svb[bi] + dvb[bi];
        key_feat[bi]   = Kv;
        value_feat[bi] = Vv;
        c = Kv * query[d * D + hd];
    }
    // seg==0 lanes (0,8,..,56) are closed under xor of bits 3..5: every seg0
    // lane of the wave ends with the full per-head logit.
    #pragma unroll
    for (int off = 8; off < 64; off <<= 1) c += __shfl_xor(c, off);

    if (seg == 0) {
        // softmax is shift-invariant; logits ~N(0,~1) -> expf safe in f32
        const float ex = expf(c);
        // unnormalized weighted aggregate: agg = (sum ex*V) / denom later
        atomicAdd(aggU + d * D + hd, ex * Vv);
        if ((tid & 63) == 0) {
            const int h = tid >> 6;          // wave index == head
            ex_out[e * H + h] = ex;          // normalized later by attn_kernel
            atomicAdd(denom + d * H + h, ex);
        }
    }
}

// ---------------------------------------------------------------------------
// Node kernel: one wave per node (4 nodes / 256-thread block).
// agg = aggU * (1/denom), then node matvec + relu + residual + layernorm.
// aggU lives in the `out` region of d_out: each wave reads its own node's
// aggregate before (program-order) overwriting it with the final output.
// ---------------------------------------------------------------------------
__global__ __launch_bounds__(256) void node_kernel(
    const float* __restrict__ in_feat, const float* __restrict__ denom,
    const float* __restrict__ node_w,  const float* __restrict__ node_b,
    const float* __restrict__ ln_w,    const float* __restrict__ ln_b,
    float* __restrict__ out)   // holds aggU on entry, final output on exit
{
    __shared__ float agg_sh[4][33];
    const int wave = threadIdx.x >> 6;
    const int lane = threadIdx.x & 63;
    const int n = blockIdx.x * 4 + wave;   // grid = N/4 exactly (N=10000)

    const int hd = lane & 31;   // 0..31: agg element (h*8+d)
    const int h  = hd >> 3;

    const float ds   = denom[n * H + h];
    const float rden = (ds != 0.0f) ? 1.0f / ds : 0.0f;  // deg==0 -> agg 0
    agg_sh[wave][hd] = out[n * D + hd] * rden;  // lanes 32..63 dup, same value
    __syncthreads();

    // matvec: o = lane>>1, half = lane&1 covers i in [half*16, half*16+16)
    const int o = lane >> 1, half = lane & 1;
    const float* w = node_w + (size_t)n * 1024 + o * 32 + half * 16;
    const float* g = &agg_sh[wave][half * 16];
    float p = 0.0f;
    #pragma unroll
    for (int j = 0; j < 16; j += 4) {
        const float4 wv = *reinterpret_cast<const float4*>(w + j);
        p += wv.x * g[j] + wv.y * g[j + 1] + wv.z * g[j + 2] + wv.w * g[j + 3];
    }
    p += __shfl_xor(p, 1);   // full dot on both lanes of the pair

    const float r = in_feat[n * D + o] + fmaxf(p + node_b[n * D + o], 0.0f);

    float sum = r, sq = r * r;
    #pragma unroll
    for (int off = 2; off < 64; off <<= 1) {
        sum += __shfl_xor(sum, off);
        sq  += __shfl_xor(sq, off);
    }
    const float mean = sum * (1.0f / 32.0f);
    const float var  = sq * (1.0f / 32.0f) - mean * mean;
    const float y = (r - mean) * rsqrtf(var + 1e-5f) * ln_w[o] + ln_b[o];
    if (half == 0) out[n * D + o] = y;
}

// ---------------------------------------------------------------------------
// Attn normalize: attn[e,h] = ex[e,h] / denom[dst[e],h]. H==4 -> one float4
// RMW per thread. denom > 0 guaranteed for any node that has an edge.
// ---------------------------------------------------------------------------
__global__ __launch_bounds__(256) void attn_kernel(
    const int* __restrict__ dst, const float* __restrict__ denom,
    float* __restrict__ attn)
{
    const int e = blockIdx.x * 256 + threadIdx.x;
    if (e < E) {
        const int d = dst[e];
        const float4 ex = *reinterpret_cast<const float4*>(attn + (size_t)e * H);
        const float4 dn = *reinterpret_cast<const float4*>(denom + (size_t)d * H);
        float4 r;
        r.x = ex.x / dn.x;
        r.y = ex.y / dn.y;
        r.z = ex.z / dn.z;
        r.w = ex.w / dn.w;
        *reinterpret_cast<float4*>(attn + (size_t)e * H) = r;
    }
}

// ---------------------------------------------------------------------------
extern "C" void kernel_launch(void* const* d_in, const int* in_sizes, int n_in,
                              void* d_out, int out_size, void* d_ws, size_t ws_size,
                              hipStream_t stream)
{
    const float* in_feat = (const float*)d_in[0];
    const int*   src     = (const int*)d_in[1];
    const int*   dst     = (const int*)d_in[2];
    const float* skw     = (const float*)d_in[3];
    const float* dkw     = (const float*)d_in[4];
    const float* skb     = (const float*)d_in[5];
    const float* dkb     = (const float*)d_in[6];
    const float* svw     = (const float*)d_in[7];
    const float* dvw     = (const float*)d_in[8];
    const float* svb     = (const float*)d_in[9];
    const float* dvb     = (const float*)d_in[10];
    const float* query   = (const float*)d_in[11];
    const float* node_w  = (const float*)d_in[12];
    const float* node_b  = (const float*)d_in[13];
    const float* ln_w    = (const float*)d_in[14];
    const float* ln_b    = (const float*)d_in[15];

    // d_out layout: out(N*D) | key_feat(E*D) | value_feat(E*D) | attn(E*H)
    float* out        = (float*)d_out;
    float* key_feat   = out + (size_t)N * D;
    float* value_feat = key_feat + (size_t)E * D;
    float* attn       = value_feat + (size_t)E * D;

    // ws layout (floats): denom[N*H] only (160 KB)
    float* denom = (float*)d_ws;

    // zero the aggregation scratch (out region doubles as aggU) + denominators
    hipMemsetAsync(out,   0, (size_t)N * D * sizeof(float), stream);
    hipMemsetAsync(denom, 0, (size_t)N * H * sizeof(float), stream);

    edge_kernel<<<E, 256, 0, stream>>>(in_feat, src, dst,
                                       skw, dkw, skb, dkb,
                                       svw, dvw, svb, dvb,
                                       query, key_feat, value_feat, attn,
                                       out, denom);

    node_kernel<<<N / 4, 256, 0, stream>>>(in_feat, denom,
                                           node_w, node_b, ln_w, ln_b, out);

    attn_kernel<<<(E + 255) / 256, 256, 0, stream>>>(dst, denom, attn);
}